// Round 8
// baseline (20.204 us; speedup 1.0000x reference)
//
#include <hip/hip_runtime.h>

// BilinearSparseRouting — collapsed form (dots = softmax(const) = 1/32 exactly):
//   S[b] (4x4) = sum_j cp_mat[b,j] @ wc[j]
//   out[b,i]   = (1/32) * S[b] @ wn[i]
//
// R8 = R7 with ONE change: per-block stream rotation. Block b walks its
// 256 KiB cp-chunk starting 1 KiB * b further in (mod chunk), so the 256 CUs
// present 256 DISTINCT low-address offsets to the HBM channel interleave at
// every instant instead of hammering the same channel subset in lockstep.
// Rotation is a bijection on the chunk -> identical sum, coalescing intact.

#define BATCH 256
#define NIN   4096
#define NOUT  32

constexpr int THREADS = 1024;
constexpr int VPT     = 4;                      // f32x4 per thread per iter
constexpr int POS     = NIN * 4;                // 16384 f32x4 positions / batch
constexpr int ITERS   = POS / (THREADS * VPT);  // 4
constexpr int WAVES   = THREADS / 64;           // 16

typedef __attribute__((ext_vector_type(4))) float f32x4;

template<int K>
__device__ __forceinline__ f32x4 quad_bcast(f32x4 x) {
    // VALU-pipe quad broadcast: v_mov_b32_dpp quad_perm:[K,K,K,K]
    constexpr int ctrl = K * 0x55;              // K|(K<<2)|(K<<4)|(K<<6)
    f32x4 r;
#pragma unroll
    for (int d = 0; d < 4; ++d)
        r[d] = __int_as_float(
            __builtin_amdgcn_mov_dpp(__float_as_int(x[d]), ctrl, 0xF, 0xF, true));
    return r;
}

__global__ __launch_bounds__(THREADS)
void caps_fused(const float* __restrict__ cp,
                const float* __restrict__ wc,
                const float* __restrict__ wn,
                float* __restrict__ out) {
    const int b    = blockIdx.x;
    const int t    = threadIdx.x;
    const int lane = t & 63;
    const int wave = t >> 6;

    const f32x4* cp4 = (const f32x4*)cp + (size_t)b * POS;
    const f32x4* wc4 = (const f32x4*)wc;

    // per-block stream rotation: +b waves (1 KiB each), wrapped in the chunk
    const int rot = (t + b * 64) & (POS - 1);

    f32x4 acc = {0.f, 0.f, 0.f, 0.f};   // row r=t&3 of S, partial

#pragma unroll
    for (int it = 0; it < ITERS; ++it) {
        f32x4 a[VPT], w[VPT];
#pragma unroll
        for (int v = 0; v < VPT; ++v) {
            const int p = (rot + it * (THREADS * VPT) + v * THREADS) & (POS - 1);
            a[v] = cp4[p];        // A_j row r   (lane-contiguous load)
            w[v] = wc4[p];        // W_j row r   (lane-contiguous load)
        }
#pragma unroll
        for (int v = 0; v < VPT; ++v) {
            const f32x4 w0 = quad_bcast<0>(w[v]);
            const f32x4 w1 = quad_bcast<1>(w[v]);
            const f32x4 w2 = quad_bcast<2>(w[v]);
            const f32x4 w3 = quad_bcast<3>(w[v]);
            // acc[c] += sum_k a[k] * W[k][c]
            acc += a[v][0] * w0;
            acc += a[v][1] * w1;
            acc += a[v][2] * w2;
            acc += a[v][3] * w3;
        }
    }

    // Sum across lanes with equal (lane&3): butterfly over masks 4,8,16,32.
#pragma unroll
    for (int m = 4; m <= 32; m <<= 1) {
#pragma unroll
        for (int c = 0; c < 4; ++c)
            acc[c] += __shfl_xor(acc[c], m, 64);
    }

    __shared__ f32x4 red[WAVES][4];
    __shared__ float S[16];
    if (lane < 4) red[wave][lane] = acc;   // lane == row r (t&3 survives rot: +b*64 doesn't change t&3)
    __syncthreads();

    if (t < 16) {                           // t = r*4 + c
        float v = 0.f;
#pragma unroll
        for (int w2 = 0; w2 < WAVES; ++w2) v += red[w2][t >> 2][t & 3];
        S[t] = v * (1.0f / 32.0f);
    }
    __syncthreads();

    // Epilogue: out[b,i,r,0..3] = S[r,:] @ wn[i][:,0..3], 128 threads x f32x4
    if (t < NOUT * 4) {
        const int i = t >> 2;
        const int r = t & 3;
        const f32x4* wn4 = (const f32x4*)(wn + i * 16);
        const f32x4 w0 = wn4[0], w1 = wn4[1], w2 = wn4[2], w3 = wn4[3];
        const float s0 = S[r * 4 + 0], s1 = S[r * 4 + 1];
        const float s2 = S[r * 4 + 2], s3 = S[r * 4 + 3];
        f32x4 o;
        o[0] = s0 * w0[0] + s1 * w1[0] + s2 * w2[0] + s3 * w3[0];
        o[1] = s0 * w0[1] + s1 * w1[1] + s2 * w2[1] + s3 * w3[1];
        o[2] = s0 * w0[2] + s1 * w1[2] + s2 * w2[2] + s3 * w3[2];
        o[3] = s0 * w0[3] + s1 * w1[3] + s2 * w2[3] + s3 * w3[3];
        ((f32x4*)(out + (size_t)b * NOUT * 16))[t] = o;
    }
}

extern "C" void kernel_launch(void* const* d_in, const int* in_sizes, int n_in,
                              void* d_out, int out_size, void* d_ws, size_t ws_size,
                              hipStream_t stream) {
    const float* cp = (const float*)d_in[0];   // (256,4096,16)
    const float* wc = (const float*)d_in[1];   // (1,1,4096,4,4)
    const float* wn = (const float*)d_in[2];   // (32,4,4)
    float* out = (float*)d_out;                // (256,1,1,32,16)

    caps_fused<<<BATCH, THREADS, 0, stream>>>(cp, wc, wn, out);
}

// Round 9
// 16.733 us; speedup vs baseline: 1.2074x; 1.2074x over previous
//
#include <hip/hip_runtime.h>

// BilinearSparseRouting — collapsed form (dots = softmax(const) = 1/32 exactly):
//   S[b] (4x4) = sum_j cp_mat[b,j] @ wc[j]
//   out[b,i]   = (1/32) * S[b] @ wn[i]
//
// R9 = R7 (best structure) with ONE change: cp loads are NONTEMPORAL.
// cp is a 64 MiB zero-reuse stream that sweeps each XCD's 4 MiB L2 twice
// over the kernel, evicting the shared 256 KiB wc tile between CU touches
// (R8's desync regression is evidence wc residency matters). nt keeps cp
// out of L2 so wc stays resident for all 32 CUs/XCD.
// Safe here (unlike R3): every cp load is lane-contiguous 1 KiB with zero
// cache-line reuse across instructions, so dropping retention costs nothing.

#define BATCH 256
#define NIN   4096
#define NOUT  32

constexpr int THREADS = 1024;
constexpr int VPT     = 4;                      // f32x4 per thread per iter
constexpr int POS     = NIN * 4;                // 16384 f32x4 positions / batch
constexpr int ITERS   = POS / (THREADS * VPT);  // 4
constexpr int WAVES   = THREADS / 64;           // 16

typedef __attribute__((ext_vector_type(4))) float f32x4;

template<int K>
__device__ __forceinline__ f32x4 quad_bcast(f32x4 x) {
    // VALU-pipe quad broadcast: v_mov_b32_dpp quad_perm:[K,K,K,K]
    constexpr int ctrl = K * 0x55;              // K|(K<<2)|(K<<4)|(K<<6)
    f32x4 r;
#pragma unroll
    for (int d = 0; d < 4; ++d)
        r[d] = __int_as_float(
            __builtin_amdgcn_mov_dpp(__float_as_int(x[d]), ctrl, 0xF, 0xF, true));
    return r;
}

__global__ __launch_bounds__(THREADS)
void caps_fused(const float* __restrict__ cp,
                const float* __restrict__ wc,
                const float* __restrict__ wn,
                float* __restrict__ out) {
    const int b    = blockIdx.x;
    const int t    = threadIdx.x;
    const int lane = t & 63;
    const int wave = t >> 6;

    const f32x4* cp4 = (const f32x4*)cp + (size_t)b * POS;
    const f32x4* wc4 = (const f32x4*)wc;

    f32x4 acc = {0.f, 0.f, 0.f, 0.f};   // row r=t&3 of S, partial

#pragma unroll
    for (int it = 0; it < ITERS; ++it) {
        f32x4 a[VPT], w[VPT];
#pragma unroll
        for (int v = 0; v < VPT; ++v) {
            const int p = it * (THREADS * VPT) + v * THREADS + t;
            a[v] = __builtin_nontemporal_load(cp4 + p);  // streaming, L2-bypass
            w[v] = wc4[p];                                // cached (shared tile)
        }
#pragma unroll
        for (int v = 0; v < VPT; ++v) {
            const f32x4 w0 = quad_bcast<0>(w[v]);
            const f32x4 w1 = quad_bcast<1>(w[v]);
            const f32x4 w2 = quad_bcast<2>(w[v]);
            const f32x4 w3 = quad_bcast<3>(w[v]);
            // acc[c] += sum_k a[k] * W[k][c]
            acc += a[v][0] * w0;
            acc += a[v][1] * w1;
            acc += a[v][2] * w2;
            acc += a[v][3] * w3;
        }
    }

    // Sum across lanes with equal (lane&3): butterfly over masks 4,8,16,32.
#pragma unroll
    for (int m = 4; m <= 32; m <<= 1) {
#pragma unroll
        for (int c = 0; c < 4; ++c)
            acc[c] += __shfl_xor(acc[c], m, 64);
    }

    __shared__ f32x4 red[WAVES][4];
    __shared__ float S[16];
    if (lane < 4) red[wave][lane] = acc;   // lane == row r
    __syncthreads();

    if (t < 16) {                           // t = r*4 + c
        float v = 0.f;
#pragma unroll
        for (int w2 = 0; w2 < WAVES; ++w2) v += red[w2][t >> 2][t & 3];
        S[t] = v * (1.0f / 32.0f);
    }
    __syncthreads();

    // Epilogue: out[b,i,r,0..3] = S[r,:] @ wn[i][:,0..3], 128 threads x f32x4
    if (t < NOUT * 4) {
        const int i = t >> 2;
        const int r = t & 3;
        const f32x4* wn4 = (const f32x4*)(wn + i * 16);
        const f32x4 w0 = wn4[0], w1 = wn4[1], w2 = wn4[2], w3 = wn4[3];
        const float s0 = S[r * 4 + 0], s1 = S[r * 4 + 1];
        const float s2 = S[r * 4 + 2], s3 = S[r * 4 + 3];
        f32x4 o;
        o[0] = s0 * w0[0] + s1 * w1[0] + s2 * w2[0] + s3 * w3[0];
        o[1] = s0 * w0[1] + s1 * w1[1] + s2 * w2[1] + s3 * w3[1];
        o[2] = s0 * w0[2] + s1 * w1[2] + s2 * w2[2] + s3 * w3[2];
        o[3] = s0 * w0[3] + s1 * w1[3] + s2 * w2[3] + s3 * w3[3];
        ((f32x4*)(out + (size_t)b * NOUT * 16))[t] = o;
    }
}

extern "C" void kernel_launch(void* const* d_in, const int* in_sizes, int n_in,
                              void* d_out, int out_size, void* d_ws, size_t ws_size,
                              hipStream_t stream) {
    const float* cp = (const float*)d_in[0];   // (256,4096,16)
    const float* wc = (const float*)d_in[1];   // (1,1,4096,4,4)
    const float* wn = (const float*)d_in[2];   // (32,4,4)
    float* out = (float*)d_out;                // (256,1,1,32,16)

    caps_fused<<<BATCH, THREADS, 0, stream>>>(cp, wc, wn, out);
}